// Round 11
// baseline (910.731 us; speedup 1.0000x reference)
//
#include <hip/hip_runtime.h>

typedef __attribute__((ext_vector_type(8))) short bf16x8;
typedef __attribute__((ext_vector_type(4))) float f32x4;

__device__ __forceinline__ unsigned short f2bf(float x){
  union { float f; unsigned u; } v; v.f = x;
  unsigned r = v.u + 0x7FFFu + ((v.u >> 16) & 1u);
  return (unsigned short)(r >> 16);
}

#define BYPASS_ST_SHORT(base, val) \
  asm volatile("global_store_short %0, %1, off sc0 sc1" :: "v"(base), "v"(val))

__device__ __forceinline__ int ld_flag(const int* p){
  int v;
  asm volatile("global_load_dword %0, %1, off sc0 sc1\n\t"
               "s_waitcnt vmcnt(0)"
               : "=v"(v) : "v"(p) : "memory");
  return v;
}

__device__ __forceinline__ void gload_lds16(const void* g, void* l){
  __builtin_amdgcn_global_load_lds(
      (const __attribute__((address_space(1))) unsigned*)g,
      (__attribute__((address_space(3))) unsigned*)l, 16, 0, 0);
}

// ---------------- embed + mask + flag reset ----------------
__global__ void embed_kernel(const int* __restrict__ seqs, const float* __restrict__ emb,
                             unsigned short* __restrict__ x, int* __restrict__ mask,
                             int* __restrict__ flags){
  const int t = blockIdx.x, b = blockIdx.y, l = threadIdx.x;
  if (t == 0 && b == 0){
    #pragma unroll
    for (int j = 0; j < 16; ++j) flags[l + j*64] = 0;   // 64 slots x 64B
  }
  const int tok = seqs[b*130 + t];
  if (l == 0) mask[b*130 + t] = (tok != 0) ? 1 : 0;
  const float* src = emb + (size_t)tok * 256;
  unsigned short* dst = x + ((size_t)b*130 + t)*256;
  #pragma unroll
  for (int j = 0; j < 4; ++j) dst[l + j*64] = f2bf(src[l + j*64]);
}

// ---------------- merged: persistent LSTM (wg 0..63) + WpT transpose (wg 64..383) ----
// LSTM: R10 structure + direct fp32->B-frag weight prologue + 4-way acc split.
// Transpose WGs grid-stride 16000 tiles of Wp[1024][32000]fp32 -> WpT[32000][1024]bf16,
// running on otherwise-idle CUs concurrently with the latency-bound LSTM.
__global__ __launch_bounds__(512, 2) void lstm_coop(
    const unsigned short* __restrict__ x, const int* __restrict__ maskg,
    const float* __restrict__ fk0, const float* __restrict__ fr0,
    const float* __restrict__ fk1, const float* __restrict__ fr1,
    const float* __restrict__ bk0, const float* __restrict__ br0,
    const float* __restrict__ bk1, const float* __restrict__ br1,
    const float* __restrict__ fb0, const float* __restrict__ fb1,
    const float* __restrict__ bb0, const float* __restrict__ bb1,
    const float* __restrict__ Wp, unsigned short* __restrict__ WpT,
    unsigned short* h0f, unsigned short* h0b,
    unsigned short* aproj, int* flags)
{
  const int wg = blockIdx.x;
  const int tid = threadIdx.x;

  __shared__ float z_lds[4][16][32];
  __shared__ int mask_s[16*130];
  __shared__ __attribute__((aligned(16))) char h_lds[16*1024];
  __shared__ __attribute__((aligned(16))) char h2_lds[16*1024];

  if (wg >= 64){
    // ---------- WpT transpose: tiles [32 k] x [64 n] ----------
    float* tf = (float*)h_lds;                        // [32][65] floats
    const int tw = wg - 64;
    const int tx = tid & 63, ty = tid >> 6;           // 64 x 8
    const int orow = tid & 31, oc = tid >> 5;         // 32 x 16
    for (int tile = tw; tile < 16000; tile += 320){
      const int kt = tile / 500, nt = tile - kt*500;
      const int r0 = kt*32, c0 = nt*64;
      #pragma unroll
      for (int j = 0; j < 4; ++j)
        tf[(ty + 8*j)*65 + tx] = Wp[(size_t)(r0 + ty + 8*j)*32000 + c0 + tx];
      __syncthreads();
      #pragma unroll
      for (int j = 0; j < 4; ++j)
        WpT[(size_t)(c0 + oc + 16*j)*1024 + r0 + orow] = f2bf(tf[orow*65 + oc + 16*j]);
      __syncthreads();
    }
    return;
  }

  // ---------- LSTM ----------
  const int dir = wg >> 5;
  const int layer = (wg >> 4) & 1;
  const int u0 = (wg & 15) * 32;
  const int w = tid >> 6, l = tid & 63;
  const int gate = w >> 1, half = w & 1;
  const int lr = l & 15, lk = l >> 4;
  const int cglob = gate*512 + u0 + half*16 + lr;

  const float* kW = (layer == 0) ? (dir ? bk0 : fk0) : (dir ? bk1 : fk1);
  const float* rW = (layer == 0) ? (dir ? br0 : fr0) : (dir ? br1 : fr1);
  const float* bias = (layer == 0) ? (dir ? bb0 : fb0) : (dir ? bb1 : fb1);
  unsigned short* h0 = dir ? h0b : h0f;

  int* fown  = flags + (layer*2 + dir)*256;
  int* fprod = flags + dir*256;
  int* fself = fown + (wg & 15)*16;

  // One-time weight prologue: B-frags straight from fp32 [K][2048] weights.
  // frag[i][j] = W[(i*32 + lk*8 + j)][cglob]  (same values+rounding as old transpose path)
  bf16x8 wreg[16], kreg[16];
  #pragma unroll
  for (int i = 0; i < 16; ++i){
    #pragma unroll
    for (int j = 0; j < 8; ++j)
      wreg[i][j] = (short)f2bf(rW[(size_t)(i*32 + lk*8 + j)*2048 + cglob]);
  }
  const int nk = (layer == 0) ? 8 : 16;
  #pragma unroll
  for (int i = 0; i < 16; ++i){
    if (i < nk){
      #pragma unroll
      for (int j = 0; j < 8; ++j)
        kreg[i][j] = (short)f2bf(kW[(size_t)(i*32 + lk*8 + j)*2048 + cglob]);
    }
  }

  for (int i = tid; i < 16*130; i += 512) mask_s[i] = maskg[i];

  float c_reg = 0.f, h_reg = 0.f;
  const int gu = tid & 31, gb = tid >> 5;
  const float bzi = bias[u0+gu], bzf = bias[512 + u0+gu];
  const float bzc = bias[1024 + u0+gu], bzo = bias[1536 + u0+gu];
  __syncthreads();

  for (int t = 0; t < 128; ++t){
    // ---- acquire ----
    if (w == 0){
      const int* fp = nullptr; int tgt = 0;
      if (l < 16){ fp = fown + l*16; tgt = t; }
      else if (l < 32 && layer == 1){ fp = fprod + (l-16)*16; tgt = t + 1; }
      if (fp){
        while (ld_flag(fp) < tgt) __builtin_amdgcn_s_sleep(1);
      }
    }
    __syncthreads();                                   // S1

    // ---- stage h into LDS once per WG (wave w: rows 2w, 2w+1) ----
    const int r0s = w*2;
    if (layer == 0){
      if (t > 0){
        #pragma unroll
        for (int j = 0; j < 2; ++j){
          const int r = r0s + j;
          const unsigned short* g = h0 + ((size_t)(t-1)*16 + r)*512 + ((l ^ (r & 7))*8);
          gload_lds16(g, h_lds + r*1024);
        }
      }
    } else {
      #pragma unroll
      for (int j = 0; j < 2; ++j){
        const int r = r0s + j;
        const unsigned short* g = h0 + ((size_t)t*16 + r)*512 + ((l ^ (r & 7))*8);
        gload_lds16(g, h_lds + r*1024);
      }
      if (t > 0){
        const int prow = dir ? (128 - t) : (t - 1);
        #pragma unroll
        for (int j = 0; j < 2; ++j){
          const int r = r0s + j;
          const unsigned short* g = aproj + ((size_t)(r*128 + prow))*1024 + dir*512 + ((l ^ (r & 7))*8);
          gload_lds16(g, h2_lds + r*1024);
        }
      }
    }

    // ---- compute z (4-way split accumulators) ----
    f32x4 a0 = {0.f,0.f,0.f,0.f}, a1 = a0, a2 = a0, a3 = a0;
    const int fsw = (lr & 7) << 4;
    if (layer == 0){
      const int pos = dir ? (129 - t) : t;
      const unsigned short* xa = x + ((size_t)lr*130 + pos)*256 + lk*8;
      #pragma unroll
      for (int i = 0; i < 8; i += 2){                  // overlaps stage latency
        bf16x8 va = *(const bf16x8*)(xa + i*32);
        bf16x8 vb = *(const bf16x8*)(xa + i*32 + 32);
        a0 = __builtin_amdgcn_mfma_f32_16x16x32_bf16(va, kreg[i],   a0, 0, 0, 0);
        a1 = __builtin_amdgcn_mfma_f32_16x16x32_bf16(vb, kreg[i+1], a1, 0, 0, 0);
      }
      if (t > 0){
        asm volatile("s_waitcnt vmcnt(0)" ::: "memory");
        __syncthreads();                               // S2
        #pragma unroll
        for (int i = 0; i < 16; i += 4){
          bf16x8 v0 = *(const bf16x8*)(h_lds + lr*1024 + ((lk*16 + (i  )*64) ^ fsw));
          bf16x8 v1 = *(const bf16x8*)(h_lds + lr*1024 + ((lk*16 + (i+1)*64) ^ fsw));
          bf16x8 v2 = *(const bf16x8*)(h_lds + lr*1024 + ((lk*16 + (i+2)*64) ^ fsw));
          bf16x8 v3 = *(const bf16x8*)(h_lds + lr*1024 + ((lk*16 + (i+3)*64) ^ fsw));
          a0 = __builtin_amdgcn_mfma_f32_16x16x32_bf16(v0, wreg[i],   a0, 0, 0, 0);
          a1 = __builtin_amdgcn_mfma_f32_16x16x32_bf16(v1, wreg[i+1], a1, 0, 0, 0);
          a2 = __builtin_amdgcn_mfma_f32_16x16x32_bf16(v2, wreg[i+2], a2, 0, 0, 0);
          a3 = __builtin_amdgcn_mfma_f32_16x16x32_bf16(v3, wreg[i+3], a3, 0, 0, 0);
        }
      }
    } else {
      asm volatile("s_waitcnt vmcnt(0)" ::: "memory");
      __syncthreads();                                 // S2
      #pragma unroll
      for (int i = 0; i < 16; i += 4){
        bf16x8 v0 = *(const bf16x8*)(h_lds + lr*1024 + ((lk*16 + (i  )*64) ^ fsw));
        bf16x8 v1 = *(const bf16x8*)(h_lds + lr*1024 + ((lk*16 + (i+1)*64) ^ fsw));
        bf16x8 v2 = *(const bf16x8*)(h_lds + lr*1024 + ((lk*16 + (i+2)*64) ^ fsw));
        bf16x8 v3 = *(const bf16x8*)(h_lds + lr*1024 + ((lk*16 + (i+3)*64) ^ fsw));
        a0 = __builtin_amdgcn_mfma_f32_16x16x32_bf16(v0, kreg[i],   a0, 0, 0, 0);
        a1 = __builtin_amdgcn_mfma_f32_16x16x32_bf16(v1, kreg[i+1], a1, 0, 0, 0);
        a2 = __builtin_amdgcn_mfma_f32_16x16x32_bf16(v2, kreg[i+2], a2, 0, 0, 0);
        a3 = __builtin_amdgcn_mfma_f32_16x16x32_bf16(v3, kreg[i+3], a3, 0, 0, 0);
      }
      if (t > 0){
        #pragma unroll
        for (int i = 0; i < 16; i += 4){
          bf16x8 v0 = *(const bf16x8*)(h2_lds + lr*1024 + ((lk*16 + (i  )*64) ^ fsw));
          bf16x8 v1 = *(const bf16x8*)(h2_lds + lr*1024 + ((lk*16 + (i+1)*64) ^ fsw));
          bf16x8 v2 = *(const bf16x8*)(h2_lds + lr*1024 + ((lk*16 + (i+2)*64) ^ fsw));
          bf16x8 v3 = *(const bf16x8*)(h2_lds + lr*1024 + ((lk*16 + (i+3)*64) ^ fsw));
          a0 = __builtin_amdgcn_mfma_f32_16x16x32_bf16(v0, wreg[i],   a0, 0, 0, 0);
          a1 = __builtin_amdgcn_mfma_f32_16x16x32_bf16(v1, wreg[i+1], a1, 0, 0, 0);
          a2 = __builtin_amdgcn_mfma_f32_16x16x32_bf16(v2, wreg[i+2], a2, 0, 0, 0);
          a3 = __builtin_amdgcn_mfma_f32_16x16x32_bf16(v3, wreg[i+3], a3, 0, 0, 0);
        }
      }
    }
    {
      f32x4 acc = (a0 + a1) + (a2 + a3);
      // C-frag: col = lane&15, row = (lane>>4)*4 + r  (verified m89/m91)
      #pragma unroll
      for (int r = 0; r < 4; ++r) z_lds[gate][lk*4 + r][half*16 + lr] = acc[r];
    }
    __syncthreads();                                   // S3

    // ---- activation + release ----
    {
      const float zi = z_lds[0][gb][gu] + bzi;
      const float zf = z_lds[1][gb][gu] + bzf;
      const float zc = z_lds[2][gb][gu] + bzc;
      const float zo = z_lds[3][gb][gu] + bzo;
      const float iv = 1.f / (1.f + expf(-zi));
      const float fv = 1.f / (1.f + expf(-zf));
      const float ov = 1.f / (1.f + expf(-zo));
      const float gv = tanhf(zc);
      float cn = fv*c_reg + iv*gv;
      float hn = ov*tanhf(cn);
      const int pos = dir ? (129 - t) : t;
      if (mask_s[gb*130 + pos] == 0){ cn = c_reg; hn = h_reg; }
      c_reg = cn; h_reg = hn;
      const unsigned short hb = f2bf(hn);
      if (layer == 0){
        unsigned short* p = h0 + ((size_t)t*16 + gb)*512 + u0 + gu;
        BYPASS_ST_SHORT(p, (unsigned)hb);
      } else {
        const int row = dir ? (127 - t) : t;
        unsigned short* p = aproj + ((size_t)gb*128 + row)*1024 + dir*512 + u0 + gu;
        BYPASS_ST_SHORT(p, (unsigned)hb);
      }
    }
    asm volatile("s_waitcnt vmcnt(0)" ::: "memory");
    __syncthreads();                                   // S4
    if (tid == 0){
      int v = t + 1;
      asm volatile("global_store_dword %0, %1, off sc0 sc1" :: "v"(fself), "v"(v) : "memory");
    }
  }
}

// ---------------- bf16 MFMA GEMM (verbatim, proven) ----------------
__global__ __launch_bounds__(256) void gemm_bf16(
    const unsigned short* __restrict__ A, const unsigned short* __restrict__ Bt,
    const float* __restrict__ bias, float* __restrict__ C,
    int M, int N, int K)
{
  __shared__ unsigned short lA[128*32], lB[128*32];
  const int tid = threadIdx.x;
  const int w = tid >> 6, l = tid & 63;
  const int wr = w >> 1, wc = w & 1;
  const int lr = l & 15, lk = l >> 4;
  const int brow = blockIdx.y * 128, bcol = blockIdx.x * 128;
  f32x4 acc[4][4] = {};
  for (int k0 = 0; k0 < K; k0 += 32){
    __syncthreads();
    #pragma unroll
    for (int j = 0; j < 2; ++j){
      const int base = w*2048 + j*1024;
      const int L = base + l*16;
      const int Lg = L ^ (((L >> 7) & 3) << 4);
      const int row = Lg >> 6, kb = Lg & 63;
      gload_lds16((const char*)(A + (size_t)(brow+row)*K + k0) + kb, (char*)lA + base);
      gload_lds16((const char*)(Bt + (size_t)(bcol+row)*K + k0) + kb, (char*)lB + base);
    }
    __syncthreads();
    bf16x8 af[4], bfr[4];
    #pragma unroll
    for (int m = 0; m < 4; ++m){
      const int L = (wr*64 + m*16 + lr)*64 + lk*16;
      const int sp = L ^ (((L >> 7) & 3) << 4);
      af[m] = *(const bf16x8*)((char*)lA + sp);
    }
    #pragma unroll
    for (int n = 0; n < 4; ++n){
      const int L = (wc*64 + n*16 + lr)*64 + lk*16;
      const int sp = L ^ (((L >> 7) & 3) << 4);
      bfr[n] = *(const bf16x8*)((char*)lB + sp);
    }
    #pragma unroll
    for (int m = 0; m < 4; ++m)
      #pragma unroll
      for (int n = 0; n < 4; ++n)
        acc[m][n] = __builtin_amdgcn_mfma_f32_16x16x32_bf16(af[m], bfr[n], acc[m][n], 0, 0, 0);
  }
  #pragma unroll
  for (int m = 0; m < 4; ++m){
    #pragma unroll
    for (int n = 0; n < 4; ++n){
      const int col = bcol + wc*64 + n*16 + lr;
      const float bv = bias[col];
      const int row0 = brow + wr*64 + m*16 + lk*4;
      #pragma unroll
      for (int r = 0; r < 4; ++r)
        C[(size_t)(row0 + r)*N + col] = acc[m][n][r] + bv;
    }
  }
}

extern "C" void kernel_launch(void* const* d_in, const int* in_sizes, int n_in,
                              void* d_out, int out_size, void* d_ws, size_t ws_size,
                              hipStream_t stream){
  (void)in_sizes; (void)n_in; (void)out_size; (void)ws_size;
  const int*   seqs = (const int*)d_in[0];
  const float* emb  = (const float*)d_in[1];
  const float* fk0  = (const float*)d_in[2];
  const float* fr0  = (const float*)d_in[3];
  const float* fb0  = (const float*)d_in[4];
  const float* fk1  = (const float*)d_in[5];
  const float* fr1  = (const float*)d_in[6];
  const float* fb1  = (const float*)d_in[7];
  const float* bk0  = (const float*)d_in[8];
  const float* br0  = (const float*)d_in[9];
  const float* bb0  = (const float*)d_in[10];
  const float* bk1  = (const float*)d_in[11];
  const float* br1  = (const float*)d_in[12];
  const float* bb1  = (const float*)d_in[13];
  const float* Wp   = (const float*)d_in[14];
  const float* bp   = (const float*)d_in[15];
  float* out = (float*)d_out;

  char* ws = (char*)d_ws;
  size_t off = 0;
  auto alloc = [&](size_t b){ size_t o = off; off += (b + 255) & ~(size_t)255; return o; };
  int* flags            = (int*)(ws + alloc(4096));
  unsigned short* x     = (unsigned short*)(ws + alloc((size_t)16*130*256*2));
  int* mask             = (int*)(ws + alloc((size_t)16*130*4));
  unsigned short* h0f   = (unsigned short*)(ws + alloc((size_t)128*16*512*2));
  unsigned short* h0b   = (unsigned short*)(ws + alloc((size_t)128*16*512*2));
  unsigned short* aproj = (unsigned short*)(ws + alloc((size_t)2048*1024*2));
  unsigned short* WpT   = (unsigned short*)(ws + alloc((size_t)32000*1024*2));

  embed_kernel<<<dim3(130,16), 64, 0, stream>>>(seqs, emb, x, mask, flags);

  lstm_coop<<<384, 512, 0, stream>>>(x, mask,
      fk0, fr0, fk1, fr1, bk0, br0, bk1, br1,
      fb0, fb1, bb0, bb1, Wp, WpT, h0f, h0b, aproj, flags);

  gemm_bf16<<<dim3(250, 16), 256, 0, stream>>>(aproj, WpT, bp, out, 2048, 32000, 1024);
}

// Round 12
// 877.998 us; speedup vs baseline: 1.0373x; 1.0373x over previous
//
#include <hip/hip_runtime.h>

typedef __attribute__((ext_vector_type(8))) short bf16x8;
typedef __attribute__((ext_vector_type(4))) float f32x4;

__device__ __forceinline__ unsigned short f2bf(float x){
  union { float f; unsigned u; } v; v.f = x;
  unsigned r = v.u + 0x7FFFu + ((v.u >> 16) & 1u);
  return (unsigned short)(r >> 16);
}

#define BYPASS_ST_SHORT(base, val) \
  asm volatile("global_store_short %0, %1, off sc0 sc1" :: "v"(base), "v"(val))

__device__ __forceinline__ int ld_flag(const int* p){
  int v;
  asm volatile("global_load_dword %0, %1, off sc0 sc1\n\t"
               "s_waitcnt vmcnt(0)"
               : "=v"(v) : "v"(p) : "memory");
  return v;
}

__device__ __forceinline__ void gload_lds16(const void* g, void* l){
  __builtin_amdgcn_global_load_lds(
      (const __attribute__((address_space(1))) unsigned*)g,
      (__attribute__((address_space(3))) unsigned*)l, 16, 0, 0);
}

// ---------------- embed + mask + flag reset ----------------
__global__ void embed_kernel(const int* __restrict__ seqs, const float* __restrict__ emb,
                             unsigned short* __restrict__ x, int* __restrict__ mask,
                             int* __restrict__ flags){
  const int t = blockIdx.x, b = blockIdx.y, l = threadIdx.x;
  if (t == 0 && b == 0){
    #pragma unroll
    for (int j = 0; j < 16; ++j) flags[l + j*64] = 0;   // 64 slots x 64B
  }
  const int tok = seqs[b*130 + t];
  if (l == 0) mask[b*130 + t] = (tok != 0) ? 1 : 0;
  const float* src = emb + (size_t)tok * 256;
  unsigned short* dst = x + ((size_t)b*130 + t)*256;
  #pragma unroll
  for (int j = 0; j < 4; ++j) dst[l + j*64] = f2bf(src[l + j*64]);
}

// ---------------- merged: persistent LSTM (wg 0..63) + WpT transpose (wg 64..255) ----
// Grid capped at 256 WGs -> one WG per CU, no co-residency with the latency-
// critical LSTM (R11's 384-WG grid doubled up on lstm CUs: 570 -> 715 us).
__global__ __launch_bounds__(512, 2) void lstm_coop(
    const unsigned short* __restrict__ x, const int* __restrict__ maskg,
    const float* __restrict__ fk0, const float* __restrict__ fr0,
    const float* __restrict__ fk1, const float* __restrict__ fr1,
    const float* __restrict__ bk0, const float* __restrict__ br0,
    const float* __restrict__ bk1, const float* __restrict__ br1,
    const float* __restrict__ fb0, const float* __restrict__ fb1,
    const float* __restrict__ bb0, const float* __restrict__ bb1,
    const float* __restrict__ Wp, unsigned short* __restrict__ WpT,
    unsigned short* h0f, unsigned short* h0b,
    unsigned short* aproj, int* flags)
{
  const int wg = blockIdx.x;
  const int tid = threadIdx.x;

  __shared__ float z_lds[4][16][32];
  __shared__ int mask_s[16*130];
  __shared__ __attribute__((aligned(16))) char h_lds[16*1024];
  __shared__ __attribute__((aligned(16))) char h2_lds[16*1024];

  if (wg >= 64){
    // ---------- WpT transpose: tiles [32 k] x [64 n], 192 WGs ----------
    float* tf = (float*)h_lds;                        // [32][65] floats
    const int tw = wg - 64;
    const int tx = tid & 63, ty = tid >> 6;           // 64 x 8
    const int orow = tid & 31, oc = tid >> 5;         // 32 x 16
    for (int tile = tw; tile < 16000; tile += 192){
      const int kt = tile / 500, nt = tile - kt*500;
      const int r0 = kt*32, c0 = nt*64;
      #pragma unroll
      for (int j = 0; j < 4; ++j)
        tf[(ty + 8*j)*65 + tx] = Wp[(size_t)(r0 + ty + 8*j)*32000 + c0 + tx];
      __syncthreads();
      #pragma unroll
      for (int j = 0; j < 4; ++j)
        WpT[(size_t)(c0 + oc + 16*j)*1024 + r0 + orow] = f2bf(tf[orow*65 + oc + 16*j]);
      __syncthreads();
    }
    return;
  }

  // ---------- LSTM ----------
  const int dir = wg >> 5;
  const int layer = (wg >> 4) & 1;
  const int u0 = (wg & 15) * 32;
  const int w = tid >> 6, l = tid & 63;
  const int gate = w >> 1, half = w & 1;
  const int lr = l & 15, lk = l >> 4;
  const int cglob = gate*512 + u0 + half*16 + lr;

  const float* kW = (layer == 0) ? (dir ? bk0 : fk0) : (dir ? bk1 : fk1);
  const float* rW = (layer == 0) ? (dir ? br0 : fr0) : (dir ? br1 : fr1);
  const float* bias = (layer == 0) ? (dir ? bb0 : fb0) : (dir ? bb1 : fb1);
  unsigned short* h0 = dir ? h0b : h0f;

  int* fown  = flags + (layer*2 + dir)*256;
  int* fprod = flags + dir*256;
  int* fself = fown + (wg & 15)*16;

  // One-time weight prologue: B-frags straight from fp32 [K][2048] weights.
  bf16x8 wreg[16], kreg[16];
  #pragma unroll
  for (int i = 0; i < 16; ++i){
    #pragma unroll
    for (int j = 0; j < 8; ++j)
      wreg[i][j] = (short)f2bf(rW[(size_t)(i*32 + lk*8 + j)*2048 + cglob]);
  }
  const int nk = (layer == 0) ? 8 : 16;
  #pragma unroll
  for (int i = 0; i < 16; ++i){
    if (i < nk){
      #pragma unroll
      for (int j = 0; j < 8; ++j)
        kreg[i][j] = (short)f2bf(kW[(size_t)(i*32 + lk*8 + j)*2048 + cglob]);
    }
  }

  for (int i = tid; i < 16*130; i += 512) mask_s[i] = maskg[i];

  float c_reg = 0.f, h_reg = 0.f;
  const int gu = tid & 31, gb = tid >> 5;
  const float bzi = bias[u0+gu], bzf = bias[512 + u0+gu];
  const float bzc = bias[1024 + u0+gu], bzo = bias[1536 + u0+gu];
  __syncthreads();

  for (int t = 0; t < 128; ++t){
    // ---- acquire ----
    if (w == 0){
      const int* fp = nullptr; int tgt = 0;
      if (l < 16){ fp = fown + l*16; tgt = t; }
      else if (l < 32 && layer == 1){ fp = fprod + (l-16)*16; tgt = t + 1; }
      if (fp){
        while (ld_flag(fp) < tgt) __builtin_amdgcn_s_sleep(1);
      }
    }
    __syncthreads();                                   // S1

    // ---- stage h into LDS once per WG (wave w: rows 2w, 2w+1) ----
    const int r0s = w*2;
    if (layer == 0){
      if (t > 0){
        #pragma unroll
        for (int j = 0; j < 2; ++j){
          const int r = r0s + j;
          const unsigned short* g = h0 + ((size_t)(t-1)*16 + r)*512 + ((l ^ (r & 7))*8);
          gload_lds16(g, h_lds + r*1024);
        }
      }
    } else {
      #pragma unroll
      for (int j = 0; j < 2; ++j){
        const int r = r0s + j;
        const unsigned short* g = h0 + ((size_t)t*16 + r)*512 + ((l ^ (r & 7))*8);
        gload_lds16(g, h_lds + r*1024);
      }
      if (t > 0){
        const int prow = dir ? (128 - t) : (t - 1);
        #pragma unroll
        for (int j = 0; j < 2; ++j){
          const int r = r0s + j;
          const unsigned short* g = aproj + ((size_t)(r*128 + prow))*1024 + dir*512 + ((l ^ (r & 7))*8);
          gload_lds16(g, h2_lds + r*1024);
        }
      }
    }

    // ---- compute z (4-way split accumulators) ----
    f32x4 a0 = {0.f,0.f,0.f,0.f}, a1 = a0, a2 = a0, a3 = a0;
    const int fsw = (lr & 7) << 4;
    if (layer == 0){
      const int pos = dir ? (129 - t) : t;
      const unsigned short* xa = x + ((size_t)lr*130 + pos)*256 + lk*8;
      #pragma unroll
      for (int i = 0; i < 8; i += 2){                  // overlaps stage latency
        bf16x8 va = *(const bf16x8*)(xa + i*32);
        bf16x8 vb = *(const bf16x8*)(xa + i*32 + 32);
        a0 = __builtin_amdgcn_mfma_f32_16x16x32_bf16(va, kreg[i],   a0, 0, 0, 0);
        a1 = __builtin_amdgcn_mfma_f32_16x16x32_bf16(vb, kreg[i+1], a1, 0, 0, 0);
      }
      if (t > 0){
        asm volatile("s_waitcnt vmcnt(0)" ::: "memory");
        __syncthreads();                               // S2
        #pragma unroll
        for (int i = 0; i < 16; i += 4){
          bf16x8 v0 = *(const bf16x8*)(h_lds + lr*1024 + ((lk*16 + (i  )*64) ^ fsw));
          bf16x8 v1 = *(const bf16x8*)(h_lds + lr*1024 + ((lk*16 + (i+1)*64) ^ fsw));
          bf16x8 v2 = *(const bf16x8*)(h_lds + lr*1024 + ((lk*16 + (i+2)*64) ^ fsw));
          bf16x8 v3 = *(const bf16x8*)(h_lds + lr*1024 + ((lk*16 + (i+3)*64) ^ fsw));
          a0 = __builtin_amdgcn_mfma_f32_16x16x32_bf16(v0, wreg[i],   a0, 0, 0, 0);
          a1 = __builtin_amdgcn_mfma_f32_16x16x32_bf16(v1, wreg[i+1], a1, 0, 0, 0);
          a2 = __builtin_amdgcn_mfma_f32_16x16x32_bf16(v2, wreg[i+2], a2, 0, 0, 0);
          a3 = __builtin_amdgcn_mfma_f32_16x16x32_bf16(v3, wreg[i+3], a3, 0, 0, 0);
        }
      }
    } else {
      asm volatile("s_waitcnt vmcnt(0)" ::: "memory");
      __syncthreads();                                 // S2
      #pragma unroll
      for (int i = 0; i < 16; i += 4){
        bf16x8 v0 = *(const bf16x8*)(h_lds + lr*1024 + ((lk*16 + (i  )*64) ^ fsw));
        bf16x8 v1 = *(const bf16x8*)(h_lds + lr*1024 + ((lk*16 + (i+1)*64) ^ fsw));
        bf16x8 v2 = *(const bf16x8*)(h_lds + lr*1024 + ((lk*16 + (i+2)*64) ^ fsw));
        bf16x8 v3 = *(const bf16x8*)(h_lds + lr*1024 + ((lk*16 + (i+3)*64) ^ fsw));
        a0 = __builtin_amdgcn_mfma_f32_16x16x32_bf16(v0, kreg[i],   a0, 0, 0, 0);
        a1 = __builtin_amdgcn_mfma_f32_16x16x32_bf16(v1, kreg[i+1], a1, 0, 0, 0);
        a2 = __builtin_amdgcn_mfma_f32_16x16x32_bf16(v2, kreg[i+2], a2, 0, 0, 0);
        a3 = __builtin_amdgcn_mfma_f32_16x16x32_bf16(v3, kreg[i+3], a3, 0, 0, 0);
      }
      if (t > 0){
        #pragma unroll
        for (int i = 0; i < 16; i += 4){
          bf16x8 v0 = *(const bf16x8*)(h2_lds + lr*1024 + ((lk*16 + (i  )*64) ^ fsw));
          bf16x8 v1 = *(const bf16x8*)(h2_lds + lr*1024 + ((lk*16 + (i+1)*64) ^ fsw));
          bf16x8 v2 = *(const bf16x8*)(h2_lds + lr*1024 + ((lk*16 + (i+2)*64) ^ fsw));
          bf16x8 v3 = *(const bf16x8*)(h2_lds + lr*1024 + ((lk*16 + (i+3)*64) ^ fsw));
          a0 = __builtin_amdgcn_mfma_f32_16x16x32_bf16(v0, wreg[i],   a0, 0, 0, 0);
          a1 = __builtin_amdgcn_mfma_f32_16x16x32_bf16(v1, wreg[i+1], a1, 0, 0, 0);
          a2 = __builtin_amdgcn_mfma_f32_16x16x32_bf16(v2, wreg[i+2], a2, 0, 0, 0);
          a3 = __builtin_amdgcn_mfma_f32_16x16x32_bf16(v3, wreg[i+3], a3, 0, 0, 0);
        }
      }
    }
    {
      f32x4 acc = (a0 + a1) + (a2 + a3);
      // C-frag: col = lane&15, row = (lane>>4)*4 + r  (verified m89/m91)
      #pragma unroll
      for (int r = 0; r < 4; ++r) z_lds[gate][lk*4 + r][half*16 + lr] = acc[r];
    }
    __syncthreads();                                   // S3

    // ---- activation + release ----
    {
      const float zi = z_lds[0][gb][gu] + bzi;
      const float zf = z_lds[1][gb][gu] + bzf;
      const float zc = z_lds[2][gb][gu] + bzc;
      const float zo = z_lds[3][gb][gu] + bzo;
      const float iv = 1.f / (1.f + expf(-zi));
      const float fv = 1.f / (1.f + expf(-zf));
      const float ov = 1.f / (1.f + expf(-zo));
      const float gv = tanhf(zc);
      float cn = fv*c_reg + iv*gv;
      float hn = ov*tanhf(cn);
      const int pos = dir ? (129 - t) : t;
      if (mask_s[gb*130 + pos] == 0){ cn = c_reg; hn = h_reg; }
      c_reg = cn; h_reg = hn;
      const unsigned short hb = f2bf(hn);
      if (layer == 0){
        unsigned short* p = h0 + ((size_t)t*16 + gb)*512 + u0 + gu;
        BYPASS_ST_SHORT(p, (unsigned)hb);
      } else {
        const int row = dir ? (127 - t) : t;
        unsigned short* p = aproj + ((size_t)gb*128 + row)*1024 + dir*512 + u0 + gu;
        BYPASS_ST_SHORT(p, (unsigned)hb);
      }
    }
    asm volatile("s_waitcnt vmcnt(0)" ::: "memory");
    __syncthreads();                                   // S4
    if (tid == 0){
      int v = t + 1;
      asm volatile("global_store_dword %0, %1, off sc0 sc1" :: "v"(fself), "v"(v) : "memory");
    }
  }
}

// ---------------- bf16 MFMA GEMM: 1-D grid, XCD-bijective chunking, M-inner ----------------
// 4000 logical blocks (250 N x 16 M). Each XCD owns 500 contiguous logical blocks
// (~31 B-panels); 16 M-blocks reuse each 256KB B-panel from that XCD's L2; A (4MB)
// is L2-resident. Cuts B re-read traffic ~16x vs the old N-fast ordering.
__global__ __launch_bounds__(256) void gemm_bf16(
    const unsigned short* __restrict__ A, const unsigned short* __restrict__ Bt,
    const float* __restrict__ bias, float* __restrict__ C,
    int M, int N, int K)
{
  __shared__ unsigned short lA[128*32], lB[128*32];
  const int tid = threadIdx.x;
  const int w = tid >> 6, l = tid & 63;
  const int wr = w >> 1, wc = w & 1;
  const int lr = l & 15, lk = l >> 4;
  const int orig = blockIdx.x;                    // 0..3999, 4000 % 8 == 0
  const int logical = (orig & 7)*500 + (orig >> 3);
  const int mt = logical & 15;                    // M inner
  const int nt = logical >> 4;                    // N-tile 0..249
  const int brow = mt * 128, bcol = nt * 128;
  f32x4 acc[4][4] = {};
  for (int k0 = 0; k0 < K; k0 += 32){
    __syncthreads();
    #pragma unroll
    for (int j = 0; j < 2; ++j){
      const int base = w*2048 + j*1024;
      const int L = base + l*16;
      const int Lg = L ^ (((L >> 7) & 3) << 4);
      const int row = Lg >> 6, kb = Lg & 63;
      gload_lds16((const char*)(A + (size_t)(brow+row)*K + k0) + kb, (char*)lA + base);
      gload_lds16((const char*)(Bt + (size_t)(bcol+row)*K + k0) + kb, (char*)lB + base);
    }
    __syncthreads();
    bf16x8 af[4], bfr[4];
    #pragma unroll
    for (int m = 0; m < 4; ++m){
      const int L = (wr*64 + m*16 + lr)*64 + lk*16;
      const int sp = L ^ (((L >> 7) & 3) << 4);
      af[m] = *(const bf16x8*)((char*)lA + sp);
    }
    #pragma unroll
    for (int n = 0; n < 4; ++n){
      const int L = (wc*64 + n*16 + lr)*64 + lk*16;
      const int sp = L ^ (((L >> 7) & 3) << 4);
      bfr[n] = *(const bf16x8*)((char*)lB + sp);
    }
    #pragma unroll
    for (int m = 0; m < 4; ++m)
      #pragma unroll
      for (int n = 0; n < 4; ++n)
        acc[m][n] = __builtin_amdgcn_mfma_f32_16x16x32_bf16(af[m], bfr[n], acc[m][n], 0, 0, 0);
  }
  #pragma unroll
  for (int m = 0; m < 4; ++m){
    #pragma unroll
    for (int n = 0; n < 4; ++n){
      const int col = bcol + wc*64 + n*16 + lr;
      const float bv = bias[col];
      const int row0 = brow + wr*64 + m*16 + lk*4;
      #pragma unroll
      for (int r = 0; r < 4; ++r)
        C[(size_t)(row0 + r)*N + col] = acc[m][n][r] + bv;
    }
  }
}

extern "C" void kernel_launch(void* const* d_in, const int* in_sizes, int n_in,
                              void* d_out, int out_size, void* d_ws, size_t ws_size,
                              hipStream_t stream){
  (void)in_sizes; (void)n_in; (void)out_size; (void)ws_size;
  const int*   seqs = (const int*)d_in[0];
  const float* emb  = (const float*)d_in[1];
  const float* fk0  = (const float*)d_in[2];
  const float* fr0  = (const float*)d_in[3];
  const float* fb0  = (const float*)d_in[4];
  const float* fk1  = (const float*)d_in[5];
  const float* fr1  = (const float*)d_in[6];
  const float* fb1  = (const float*)d_in[7];
  const float* bk0  = (const float*)d_in[8];
  const float* br0  = (const float*)d_in[9];
  const float* bb0  = (const float*)d_in[10];
  const float* bk1  = (const float*)d_in[11];
  const float* br1  = (const float*)d_in[12];
  const float* bb1  = (const float*)d_in[13];
  const float* Wp   = (const float*)d_in[14];
  const float* bp   = (const float*)d_in[15];
  float* out = (float*)d_out;

  char* ws = (char*)d_ws;
  size_t off = 0;
  auto alloc = [&](size_t b){ size_t o = off; off += (b + 255) & ~(size_t)255; return o; };
  int* flags            = (int*)(ws + alloc(4096));
  unsigned short* x     = (unsigned short*)(ws + alloc((size_t)16*130*256*2));
  int* mask             = (int*)(ws + alloc((size_t)16*130*4));
  unsigned short* h0f   = (unsigned short*)(ws + alloc((size_t)128*16*512*2));
  unsigned short* h0b   = (unsigned short*)(ws + alloc((size_t)128*16*512*2));
  unsigned short* aproj = (unsigned short*)(ws + alloc((size_t)2048*1024*2));
  unsigned short* WpT   = (unsigned short*)(ws + alloc((size_t)32000*1024*2));

  embed_kernel<<<dim3(130,16), 64, 0, stream>>>(seqs, emb, x, mask, flags);

  lstm_coop<<<256, 512, 0, stream>>>(x, mask,
      fk0, fr0, fk1, fr1, bk0, br0, bk1, br1,
      fb0, fb1, bb0, bb1, Wp, WpT, h0f, h0b, aproj, flags);

  gemm_bf16<<<4000, 256, 0, stream>>>(aproj, WpT, bp, out, 2048, 32000, 1024);
}